// Round 1
// baseline (369.837 us; speedup 1.0000x reference)
//
#include <hip/hip_runtime.h>
#include <hip/hip_bf16.h>

typedef __attribute__((ext_vector_type(4))) float f32x4;
typedef __attribute__((ext_vector_type(8))) short s16x8;

#define NCLS 16
#define NCAT 4096
#define NOUT 512
#define NBS  4096

#define BM 128
#define BN 128
#define BK 64
#define NSPLIT 2
#define KSPLIT (NCAT / NSPLIT)
#define MAXTILES 48

// d_ws int layout
#define WS_NT    0
#define WS_CBASE 1     // [17]
#define WS_TCLS  32    // [MAXTILES]
#define WS_TM0   96    // [MAXTILES]
#define WS_SIDX  160   // [4096]

__global__ __launch_bounds__(256) void prep_kernel(const int* __restrict__ cls,
                                                   int* __restrict__ ws) {
  __shared__ int cnt[NCLS];
  __shared__ int cur[NCLS];
  __shared__ int cb[NCLS + 1];
  const int t = threadIdx.x;
  if (t < NCLS) { cnt[t] = 0; cur[t] = 0; }
  __syncthreads();
  for (int i = t; i < NBS; i += 256) atomicAdd(&cnt[cls[i]], 1);
  __syncthreads();
  if (t == 0) {
    int acc = 0, nt = 0;
    for (int c = 0; c < NCLS; ++c) {
      cb[c] = acc;
      ws[WS_CBASE + c] = acc;
      for (int m0 = 0; m0 < cnt[c]; m0 += BM) {
        ws[WS_TCLS + nt] = c;
        ws[WS_TM0 + nt] = m0;
        ++nt;
      }
      acc += cnt[c];
    }
    cb[NCLS] = acc;
    ws[WS_CBASE + NCLS] = acc;
    ws[WS_NT] = nt;
  }
  __syncthreads();
  for (int i = t; i < NBS; i += 256) {
    int c = cls[i];
    int p = atomicAdd(&cur[c], 1);
    ws[WS_SIDX + cb[c] + p] = i;
  }
}

// Split x into hi = bf16_rn(x), lo = bf16_rn(x - hi); packed pairs.
__device__ __forceinline__ void pk2(float x0, float x1, unsigned& hb, unsigned& lb) {
  __hip_bfloat162 h2 = __float22bfloat162_rn(make_float2(x0, x1));
  float2 hf = __bfloat1622float2(h2);
  __hip_bfloat162 l2 = __float22bfloat162_rn(make_float2(x0 - hf.x, x1 - hf.y));
  __builtin_memcpy(&hb, &h2, 4);
  __builtin_memcpy(&lb, &l2, 4);
}

__device__ __forceinline__ void cvt8(float4 a, float4 b, uint4& hi, uint4& lo) {
  pk2(a.x, a.y, hi.x, lo.x);
  pk2(a.z, a.w, hi.y, lo.y);
  pk2(b.x, b.y, hi.z, lo.z);
  pk2(b.z, b.w, hi.w, lo.w);
}

__global__ __launch_bounds__(256) void gemm_kernel(const float* __restrict__ batch,
                                                   const float* __restrict__ W,
                                                   const int* __restrict__ ws,
                                                   float* __restrict__ out) {
  const int tile = blockIdx.x;
  if (tile >= ws[WS_NT]) return;
  const int c    = ws[WS_TCLS + tile];
  const int m0   = ws[WS_TM0 + tile];
  const int base = ws[WS_CBASE + c];
  const int Mc   = ws[WS_CBASE + c + 1] - base;
  const int n0   = blockIdx.y * BN;
  const int k0   = blockIdx.z * KSPLIT;
  const int* sidx = ws + WS_SIDX + base;

  __shared__ char lds[4 * BM * BK * 2];  // 64 KiB: Ahi, Alo, Bhi, Blo [128][64] bf16
  char* const Ahi = lds;
  char* const Alo = lds + 16384;
  char* const Bhi = lds + 32768;
  char* const Blo = lds + 49152;

  const int t = threadIdx.x;
  // staging: 2 threads per row, each covers 32 contiguous k (fp32)
  const int r = t >> 1;
  const int h = t & 1;
  const int arow = sidx[min(m0 + r, Mc - 1)];
  const float* aptr = batch + (size_t)arow * NCAT + k0 + h * 32;
  const float* bptr = W + ((size_t)c * NOUT + (n0 + r)) * NCAT + k0 + h * 32;
  const int wswz = (r & 4) << 3;  // st_16x32-style XOR swizzle bit (32B)

  const int lane = t & 63;
  const int wv   = t >> 6;
  const int wm   = (wv >> 1) * 64;  // wave tile origin (m)
  const int wn   = (wv & 1) * 64;   // wave tile origin (n)
  const int l15  = lane & 15;
  const int kg16 = (lane >> 4) * 16;  // byte offset of lane's k-group within a k-step

  f32x4 acc[4][4];
  #pragma unroll
  for (int i = 0; i < 4; ++i)
    #pragma unroll
    for (int j = 0; j < 4; ++j) acc[i][j] = (f32x4){0.f, 0.f, 0.f, 0.f};

  for (int kt = 0; kt < KSPLIT; kt += BK) {
    __syncthreads();
    // ---- stage: global fp32 -> (hi,lo) bf16 in LDS, swizzled ----
    #pragma unroll
    for (int cc = 0; cc < 4; ++cc) {
      const int koff = kt + cc * 8;
      float4 a0 = *(const float4*)(aptr + koff);
      float4 a1 = *(const float4*)(aptr + koff + 4);
      float4 b0 = *(const float4*)(bptr + koff);
      float4 b1 = *(const float4*)(bptr + koff + 4);
      uint4 ah, al, bh, bl;
      cvt8(a0, a1, ah, al);
      cvt8(b0, b1, bh, bl);
      const int off = r * 128 + ((h * 64 + cc * 16) ^ wswz);
      *(uint4*)(Ahi + off) = ah;
      *(uint4*)(Alo + off) = al;
      *(uint4*)(Bhi + off) = bh;
      *(uint4*)(Blo + off) = bl;
    }
    __syncthreads();
    // ---- compute: 2 k-steps of 32, 16 frag-pairs x 3 MFMA ----
    #pragma unroll
    for (int ks = 0; ks < 2; ++ks) {
      s16x8 ahf[4], alf[4], bhf[4], blf[4];
      #pragma unroll
      for (int i = 0; i < 4; ++i) {
        const int m = wm + i * 16 + l15;
        const int offa = m * 128 + ((ks * 64 + kg16) ^ ((m & 4) << 3));
        ahf[i] = *(const s16x8*)(Ahi + offa);
        alf[i] = *(const s16x8*)(Alo + offa);
        const int n = wn + i * 16 + l15;
        const int offb = n * 128 + ((ks * 64 + kg16) ^ ((n & 4) << 3));
        bhf[i] = *(const s16x8*)(Bhi + offb);
        blf[i] = *(const s16x8*)(Blo + offb);
      }
      #pragma unroll
      for (int i = 0; i < 4; ++i)
        #pragma unroll
        for (int j = 0; j < 4; ++j) {
          acc[i][j] = __builtin_amdgcn_mfma_f32_16x16x32_bf16(ahf[i], bhf[j], acc[i][j], 0, 0, 0);
          acc[i][j] = __builtin_amdgcn_mfma_f32_16x16x32_bf16(ahf[i], blf[j], acc[i][j], 0, 0, 0);
          acc[i][j] = __builtin_amdgcn_mfma_f32_16x16x32_bf16(alf[i], bhf[j], acc[i][j], 0, 0, 0);
        }
    }
  }

  // ---- epilogue: C/D layout col=lane&15, row=(lane>>4)*4+reg ----
  const int r4 = (lane >> 4) * 4;
  #pragma unroll
  for (int i = 0; i < 4; ++i) {
    #pragma unroll
    for (int jj = 0; jj < 4; ++jj) {
      const int mloc = wm + i * 16 + r4 + jj;
      const int gm = m0 + mloc;
      if (gm < Mc) {
        const int sample = sidx[gm];
        float* orow = out + (size_t)sample * NOUT + n0 + wn;
        #pragma unroll
        for (int j = 0; j < 4; ++j) {
          atomicAdd(orow + j * 16 + l15, acc[i][j][jj]);
        }
      }
    }
  }
}

extern "C" void kernel_launch(void* const* d_in, const int* in_sizes, int n_in,
                              void* d_out, int out_size, void* d_ws, size_t ws_size,
                              hipStream_t stream) {
  const float* batch = (const float*)d_in[0];
  const int*   cls   = (const int*)d_in[1];
  const float* W     = (const float*)d_in[2];
  float* out = (float*)d_out;
  int*   ws  = (int*)d_ws;

  prep_kernel<<<1, 256, 0, stream>>>(cls, ws);
  hipMemsetAsync(d_out, 0, (size_t)out_size * sizeof(float), stream);
  gemm_kernel<<<dim3(MAXTILES, NOUT / BN, NSPLIT), 256, 0, stream>>>(batch, W, ws, out);
}

// Round 2
// 365.772 us; speedup vs baseline: 1.0111x; 1.0111x over previous
//
#include <hip/hip_runtime.h>
#include <hip/hip_bf16.h>

typedef __attribute__((ext_vector_type(4))) float f32x4;
typedef __attribute__((ext_vector_type(8))) short s16x8;

#define NCLS 16
#define NCAT 4096
#define NOUT 512
#define NBS  4096

#define BM 128
#define BN 128
#define BK 64
#define NSPLIT 4
#define KSPLIT (NCAT / NSPLIT)
#define NITER  (KSPLIT / BK)
#define MAXTILES 48

// d_ws int layout
#define WS_NT    0
#define WS_CBASE 1     // [17]
#define WS_TCLS  32    // [MAXTILES]
#define WS_TM0   96    // [MAXTILES]
#define WS_SIDX  160   // [4096]

// ---------------- prep: histogram + tile map + scatter, no atomics ----------------
__global__ __launch_bounds__(256) void prep_kernel(const int* __restrict__ cls,
                                                   int* __restrict__ ws) {
  __shared__ int lcnt[NCLS * 256];   // exclusive per-thread prefix after scan
  __shared__ int cb[NCLS];
  __shared__ int ctot[NCLS];
  const int t = threadIdx.x;

  int cl[16];
  #pragma unroll
  for (int j = 0; j < 16; ++j) cl[j] = cls[j * 256 + t];

  int cnt[NCLS];
  #pragma unroll
  for (int c = 0; c < NCLS; ++c) cnt[c] = 0;
  #pragma unroll
  for (int j = 0; j < 16; ++j) {
    #pragma unroll
    for (int c = 0; c < NCLS; ++c) cnt[c] += (cl[j] == c) ? 1 : 0;
  }
  #pragma unroll
  for (int c = 0; c < NCLS; ++c) lcnt[c * 256 + t] = cnt[c];
  __syncthreads();

  if (t < NCLS) {  // serial exclusive scan per class, 16 lanes in parallel
    int run = 0;
    for (int u = 0; u < 256; ++u) {
      int v = lcnt[t * 256 + u];
      lcnt[t * 256 + u] = run;
      run += v;
    }
    ctot[t] = run;
  }
  __syncthreads();

  if (t == 0) {
    int acc = 0, nt_ = 0;
    for (int c = 0; c < NCLS; ++c) {
      cb[c] = acc;
      ws[WS_CBASE + c] = acc;
      for (int m0 = 0; m0 < ctot[c]; m0 += BM) {
        ws[WS_TCLS + nt_] = c;
        ws[WS_TM0 + nt_] = m0;
        ++nt_;
      }
      acc += ctot[c];
    }
    ws[WS_CBASE + NCLS] = acc;
    ws[WS_NT] = nt_;
  }
  __syncthreads();

  // deterministic scatter: pos = cb[c] + prefix[c][t] + (#earlier same-class in this thread)
  #pragma unroll
  for (int j = 0; j < 16; ++j) {
    int c = cl[j];
    int within = 0;
    #pragma unroll
    for (int j2 = 0; j2 < 16; ++j2) within += (j2 < j && cl[j2] == c) ? 1 : 0;
    ws[WS_SIDX + cb[c] + lcnt[c * 256 + t] + within] = j * 256 + t;
  }
}

// Split x into hi = bf16_rn(x), lo = bf16_rn(x - hi); packed pairs.
__device__ __forceinline__ void pk2(float x0, float x1, unsigned& hb, unsigned& lb) {
  __hip_bfloat162 h2 = __float22bfloat162_rn(make_float2(x0, x1));
  float2 hf = __bfloat1622float2(h2);
  __hip_bfloat162 l2 = __float22bfloat162_rn(make_float2(x0 - hf.x, x1 - hf.y));
  __builtin_memcpy(&hb, &h2, 4);
  __builtin_memcpy(&lb, &l2, 4);
}

__device__ __forceinline__ void cvt8(float4 a, float4 b, uint4& hi, uint4& lo) {
  pk2(a.x, a.y, hi.x, lo.x);
  pk2(a.z, a.w, hi.y, lo.y);
  pk2(b.x, b.y, hi.z, lo.z);
  pk2(b.z, b.w, hi.w, lo.w);
}

__global__ __launch_bounds__(256, 2) void gemm_kernel(const float* __restrict__ batch,
                                                      const float* __restrict__ W,
                                                      const int* __restrict__ ws,
                                                      float* __restrict__ out) {
  const int tile = blockIdx.x;
  if (tile >= ws[WS_NT]) return;
  const int c    = ws[WS_TCLS + tile];
  const int m0   = ws[WS_TM0 + tile];
  const int base = ws[WS_CBASE + c];
  const int Mc   = ws[WS_CBASE + c + 1] - base;
  const int n0   = blockIdx.y * BN;
  const int k0   = blockIdx.z * KSPLIT;
  const int* sidx = ws + WS_SIDX + base;

  __shared__ char lds[4 * BM * BK * 2];  // 64 KiB: Ahi, Alo, Bhi, Blo [128][64] bf16
  char* const Ahi = lds;
  char* const Alo = lds + 16384;
  char* const Bhi = lds + 32768;
  char* const Blo = lds + 49152;

  const int t = threadIdx.x;
  // staging: 2 threads per row, each covers 32 contiguous k (fp32)
  const int r = t >> 1;
  const int h = t & 1;
  const int arow = sidx[min(m0 + r, Mc - 1)];
  const float* aptr = batch + (size_t)arow * NCAT + k0 + h * 32;
  const float* bptr = W + ((size_t)c * NOUT + (n0 + r)) * NCAT + k0 + h * 32;
  const int wswz = (r & 7) << 4;  // 3-bit XOR swizzle over the 128B row

  const int lane = t & 63;
  const int wv   = t >> 6;
  const int wm   = (wv >> 1) * 64;
  const int wn   = (wv & 1) * 64;
  const int l15  = lane & 15;
  const int kg16 = (lane >> 4) * 16;

  f32x4 acc[4][4];
  #pragma unroll
  for (int i = 0; i < 4; ++i)
    #pragma unroll
    for (int j = 0; j < 4; ++j) acc[i][j] = (f32x4){0.f, 0.f, 0.f, 0.f};

  // register prefetch buffers (T14: issue-early / convert-late)
  float4 pa0[4], pa1[4], pb0[4], pb1[4];
  #pragma unroll
  for (int cc = 0; cc < 4; ++cc) {
    const int ko = cc * 8;
    pa0[cc] = *(const float4*)(aptr + ko);
    pa1[cc] = *(const float4*)(aptr + ko + 4);
    pb0[cc] = *(const float4*)(bptr + ko);
    pb1[cc] = *(const float4*)(bptr + ko + 4);
  }

  for (int it = 0; it < NITER; ++it) {
    __syncthreads();  // previous compute done reading LDS
    // ---- convert staged regs -> (hi,lo) bf16 in LDS, swizzled ----
    #pragma unroll
    for (int cc = 0; cc < 4; ++cc) {
      uint4 ah, al, bh, bl;
      cvt8(pa0[cc], pa1[cc], ah, al);
      cvt8(pb0[cc], pb1[cc], bh, bl);
      const int off = r * 128 + ((h * 64 + cc * 16) ^ wswz);
      *(uint4*)(Ahi + off) = ah;
      *(uint4*)(Alo + off) = al;
      *(uint4*)(Bhi + off) = bh;
      *(uint4*)(Blo + off) = bl;
    }
    // ---- issue next tile's global loads; in flight across barrier+compute ----
    if (it + 1 < NITER) {
      const int kt = (it + 1) * BK;
      #pragma unroll
      for (int cc = 0; cc < 4; ++cc) {
        const int ko = kt + cc * 8;
        pa0[cc] = *(const float4*)(aptr + ko);
        pa1[cc] = *(const float4*)(aptr + ko + 4);
        pb0[cc] = *(const float4*)(bptr + ko);
        pb1[cc] = *(const float4*)(bptr + ko + 4);
      }
    }
    __syncthreads();  // LDS writes visible
    // ---- compute: 2 k-steps of 32, 16 frag-pairs x 3 MFMA ----
    #pragma unroll
    for (int ks = 0; ks < 2; ++ks) {
      s16x8 ahf[4], alf[4], bhf[4], blf[4];
      #pragma unroll
      for (int i = 0; i < 4; ++i) {
        const int m = wm + i * 16 + l15;
        const int offa = m * 128 + ((ks * 64 + kg16) ^ ((m & 7) << 4));
        ahf[i] = *(const s16x8*)(Ahi + offa);
        alf[i] = *(const s16x8*)(Alo + offa);
        const int n = wn + i * 16 + l15;
        const int offb = n * 128 + ((ks * 64 + kg16) ^ ((n & 7) << 4));
        bhf[i] = *(const s16x8*)(Bhi + offb);
        blf[i] = *(const s16x8*)(Blo + offb);
      }
      #pragma unroll
      for (int i = 0; i < 4; ++i)
        #pragma unroll
        for (int j = 0; j < 4; ++j) {
          acc[i][j] = __builtin_amdgcn_mfma_f32_16x16x32_bf16(ahf[i], bhf[j], acc[i][j], 0, 0, 0);
          acc[i][j] = __builtin_amdgcn_mfma_f32_16x16x32_bf16(ahf[i], blf[j], acc[i][j], 0, 0, 0);
          acc[i][j] = __builtin_amdgcn_mfma_f32_16x16x32_bf16(alf[i], bhf[j], acc[i][j], 0, 0, 0);
        }
    }
  }

  // ---- epilogue: C/D layout col=lane&15, row=(lane>>4)*4+reg ----
  const int r4 = (lane >> 4) * 4;
  #pragma unroll
  for (int i = 0; i < 4; ++i) {
    #pragma unroll
    for (int jj = 0; jj < 4; ++jj) {
      const int mloc = wm + i * 16 + r4 + jj;
      const int gm = m0 + mloc;
      if (gm < Mc) {
        const int sample = sidx[gm];
        float* orow = out + (size_t)sample * NOUT + n0 + wn;
        #pragma unroll
        for (int j = 0; j < 4; ++j) {
          atomicAdd(orow + j * 16 + l15, acc[i][j][jj]);
        }
      }
    }
  }
}

extern "C" void kernel_launch(void* const* d_in, const int* in_sizes, int n_in,
                              void* d_out, int out_size, void* d_ws, size_t ws_size,
                              hipStream_t stream) {
  const float* batch = (const float*)d_in[0];
  const int*   cls   = (const int*)d_in[1];
  const float* W     = (const float*)d_in[2];
  float* out = (float*)d_out;
  int*   ws  = (int*)d_ws;

  prep_kernel<<<1, 256, 0, stream>>>(cls, ws);
  hipMemsetAsync(d_out, 0, (size_t)out_size * sizeof(float), stream);
  gemm_kernel<<<dim3(MAXTILES, NOUT / BN, NSPLIT), 256, 0, stream>>>(batch, W, ws, out);
}

// Round 3
// 314.539 us; speedup vs baseline: 1.1758x; 1.1629x over previous
//
#include <hip/hip_runtime.h>
#include <hip/hip_bf16.h>

typedef __attribute__((ext_vector_type(4))) float f32x4;
typedef __attribute__((ext_vector_type(8))) short s16x8;

#define NCLS 16
#define NCAT 4096
#define NOUT 512
#define NBS  4096

#define BM 128
#define BN 128
#define BK 32
#define NSPLIT 4
#define KSPLIT (NCAT / NSPLIT)   // 1024
#define NIT    (KSPLIT / BK)     // 32
#define MAXTILES 48

// d_ws int layout
#define WS_NT    0
#define WS_CBASE 1     // [17]
#define WS_TCLS  32    // [MAXTILES]
#define WS_TM0   96    // [MAXTILES]
#define WS_SIDX  160   // [4096]

// ---------------- prep: histogram + parallel scan + tile map + scatter ----------------
__global__ __launch_bounds__(256) void prep_kernel(const int* __restrict__ cls,
                                                   int* __restrict__ ws) {
  __shared__ int lcnt[NCLS * 256];
  __shared__ int cb[NCLS];
  const int t = threadIdx.x;

  int cl[16];
  #pragma unroll
  for (int j = 0; j < 16; ++j) cl[j] = cls[j * 256 + t];

  int cnt[NCLS];
  #pragma unroll
  for (int c = 0; c < NCLS; ++c) cnt[c] = 0;
  #pragma unroll
  for (int j = 0; j < 16; ++j) {
    #pragma unroll
    for (int c = 0; c < NCLS; ++c) cnt[c] += (cl[j] == c) ? 1 : 0;
  }
  #pragma unroll
  for (int c = 0; c < NCLS; ++c) lcnt[c * 256 + t] = cnt[c];
  __syncthreads();

  // Hillis-Steele inclusive scan over t for all 16 classes at once
  for (int d = 1; d < 256; d <<= 1) {
    int add[NCLS];
    #pragma unroll
    for (int c = 0; c < NCLS; ++c) add[c] = (t >= d) ? lcnt[c * 256 + t - d] : 0;
    __syncthreads();
    #pragma unroll
    for (int c = 0; c < NCLS; ++c) if (t >= d) lcnt[c * 256 + t] += add[c];
    __syncthreads();
  }

  if (t == 0) {
    int acc = 0, ntt = 0;
    for (int c = 0; c < NCLS; ++c) {
      cb[c] = acc;
      ws[WS_CBASE + c] = acc;
      int tot = lcnt[c * 256 + 255];
      for (int m0 = 0; m0 < tot; m0 += BM) {
        ws[WS_TCLS + ntt] = c;
        ws[WS_TM0 + ntt] = m0;
        ++ntt;
      }
      acc += tot;
    }
    ws[WS_CBASE + NCLS] = acc;
    ws[WS_NT] = ntt;
  }
  __syncthreads();

  // deterministic scatter: pos = cb[c] + (inclusive[t] - own) + #earlier-in-thread
  #pragma unroll
  for (int j = 0; j < 16; ++j) {
    int c = cl[j];
    int within = 0;
    #pragma unroll
    for (int j2 = 0; j2 < 16; ++j2) within += (j2 < j && cl[j2] == c) ? 1 : 0;
    ws[WS_SIDX + cb[c] + (lcnt[c * 256 + t] - cnt[c]) + within] = j * 256 + t;
  }
}

// ---------------- gemm helpers ----------------
typedef const __attribute__((address_space(1))) void* gas_ptr;
typedef __attribute__((address_space(3))) void* las_ptr;

__device__ __forceinline__ void gl_lds16(const void* g, void* l) {
  __builtin_amdgcn_global_load_lds((gas_ptr)g, (las_ptr)l, 16, 0, 0);
}

// Split x into hi = bf16_rn(x), lo = bf16_rn(x - hi); packed pairs.
__device__ __forceinline__ void pk2(float x0, float x1, unsigned& hb, unsigned& lb) {
  __hip_bfloat162 h2 = __float22bfloat162_rn(make_float2(x0, x1));
  float2 hf = __bfloat1622float2(h2);
  __hip_bfloat162 l2 = __float22bfloat162_rn(make_float2(x0 - hf.x, x1 - hf.y));
  __builtin_memcpy(&hb, &h2, 4);
  __builtin_memcpy(&lb, &l2, 4);
}

__device__ __forceinline__ void cvt8(f32x4 p, f32x4 q, s16x8& hi, s16x8& lo) {
  union { s16x8 v; unsigned u[4]; } H, L;
  pk2(p[0], p[1], H.u[0], L.u[0]);
  pk2(p[2], p[3], H.u[1], L.u[1]);
  pk2(q[0], q[1], H.u[2], L.u[2]);
  pk2(q[2], q[3], H.u[3], L.u[3]);
  hi = H.v; lo = L.v;
}

// ---------------- grouped GEMM: fp32-in-LDS, async DMA, dbuf, counted vmcnt ----------------
__global__ __launch_bounds__(256, 2) void gemm_kernel(const float* __restrict__ batch,
                                                      const float* __restrict__ W,
                                                      const int* __restrict__ ws,
                                                      float* __restrict__ out) {
  const int tile = blockIdx.x;
  if (tile >= ws[WS_NT]) return;
  const int c    = ws[WS_TCLS + tile];
  const int m0   = ws[WS_TM0 + tile];
  const int base = ws[WS_CBASE + c];
  const int Mc   = ws[WS_CBASE + c + 1] - base;
  const int n0   = blockIdx.y * BN;
  const int k0   = blockIdx.z * KSPLIT;
  const int* sidx = ws + WS_SIDX + base;

  // LDS: [buf2][ A 128x32 fp32 (16KB) | B 128x32 fp32 (16KB) ]
  __shared__ char lds[65536];

  const int t    = threadIdx.x;
  const int lane = t & 63;
  const int wv   = t >> 6;
  const int l15  = lane & 15;

  // --- DMA source addresses (pre-swizzled so linear LDS dest == swizzled layout) ---
  // One gl_lds16 instr = 1024B = 8 rows of 128B. Lane l: row +(l>>3), 16B chunk (l&7).
  // LDS[r][o] must hold global[r][o ^ ((r&7)<<4)]  ->  source chunk = (l&7)^(l>>3).
  const int rsub = lane >> 3;
  const int ko   = (((lane & 7) ^ rsub) << 4);
  const char* aga[4];
  const char* bga[4];
  #pragma unroll
  for (int j = 0; j < 4; ++j) {
    const int rr = 32 * wv + 8 * j + rsub;
    const int ar = sidx[min(m0 + rr, Mc - 1)];
    aga[j] = (const char*)batch + ((size_t)ar * NCAT + k0) * 4 + ko;
    const int br = c * NOUT + n0 + rr;
    bga[j] = (const char*)W + ((size_t)br * NCAT + k0) * 4 + ko;
  }

  char* const stA = lds + (32 * wv) * 128;  // this wave's staging base (A), +16384 for B

  const int wm  = (wv >> 1) * 64;
  const int wn  = (wv & 1) * 64;
  const int kb0 = (lane >> 4) * 32;  // fragment byte base within 128B row (8 fp32)

  f32x4 acc[4][4];
  #pragma unroll
  for (int i = 0; i < 4; ++i)
    #pragma unroll
    for (int j = 0; j < 4; ++j) acc[i][j] = (f32x4){0.f, 0.f, 0.f, 0.f};

  // prologue: issue tiles 0 and 1 (8 DMA instrs each per wave-quarter)
  #pragma unroll
  for (int j = 0; j < 4; ++j) {
    gl_lds16(aga[j] + 0 * 128, stA + j * 1024);
    gl_lds16(bga[j] + 0 * 128, stA + 16384 + j * 1024);
  }
  #pragma unroll
  for (int j = 0; j < 4; ++j) {
    gl_lds16(aga[j] + 1 * 128, stA + 32768 + j * 1024);
    gl_lds16(bga[j] + 1 * 128, stA + 32768 + 16384 + j * 1024);
  }

  for (int it = 0; it < NIT; ++it) {
    // wait for tile it's 8 DMAs (keep the next tile's 8 in flight — never drain to 0)
    if (it < NIT - 1) asm volatile("s_waitcnt vmcnt(8)" ::: "memory");
    else              asm volatile("s_waitcnt vmcnt(0)" ::: "memory");
    __builtin_amdgcn_s_barrier();
    asm volatile("" ::: "memory");

    {
      const char* const bufp = lds + (it & 1) * 32768;
      s16x8 Ah[4], Al[4], Bh[4], Bl[4];
      #pragma unroll
      for (int i = 0; i < 4; ++i) {
        const int m = wm + i * 16 + l15;
        const char* rowp = bufp + m * 128;
        const int swzm = (m & 7) << 4;
        f32x4 p = *(const f32x4*)(rowp + ((kb0) ^ swzm));
        f32x4 q = *(const f32x4*)(rowp + ((kb0 + 16) ^ swzm));
        cvt8(p, q, Ah[i], Al[i]);
        const int n = wn + i * 16 + l15;
        const char* rowq = bufp + 16384 + n * 128;
        const int swzn = (n & 7) << 4;
        f32x4 r = *(const f32x4*)(rowq + ((kb0) ^ swzn));
        f32x4 s = *(const f32x4*)(rowq + ((kb0 + 16) ^ swzn));
        cvt8(r, s, Bh[i], Bl[i]);
      }
      #pragma unroll
      for (int i = 0; i < 4; ++i)
        #pragma unroll
        for (int j = 0; j < 4; ++j) {
          acc[i][j] = __builtin_amdgcn_mfma_f32_16x16x32_bf16(Ah[i], Bh[j], acc[i][j], 0, 0, 0);
          acc[i][j] = __builtin_amdgcn_mfma_f32_16x16x32_bf16(Ah[i], Bl[j], acc[i][j], 0, 0, 0);
          acc[i][j] = __builtin_amdgcn_mfma_f32_16x16x32_bf16(Al[i], Bh[j], acc[i][j], 0, 0, 0);
        }
    }

    asm volatile("" ::: "memory");
    __builtin_amdgcn_s_barrier();
    // all waves done reading buf[it&1]; refill it with tile it+2
    if (it + 2 < NIT) {
      char* const dst = lds + (it & 1) * 32768 + (32 * wv) * 128;
      const int koff = (it + 2) * 128;
      #pragma unroll
      for (int j = 0; j < 4; ++j) {
        gl_lds16(aga[j] + koff, dst + j * 1024);
        gl_lds16(bga[j] + koff, dst + 16384 + j * 1024);
      }
    }
  }

  // ---- epilogue: C/D layout col=lane&15, row=(lane>>4)*4+reg ----
  const int r4 = (lane >> 4) * 4;
  #pragma unroll
  for (int i = 0; i < 4; ++i) {
    #pragma unroll
    for (int jj = 0; jj < 4; ++jj) {
      const int mloc = wm + i * 16 + r4 + jj;
      const int gm = m0 + mloc;
      if (gm < Mc) {
        const int sample = sidx[gm];
        float* orow = out + (size_t)sample * NOUT + n0 + wn;
        #pragma unroll
        for (int j = 0; j < 4; ++j) {
          atomicAdd(orow + j * 16 + l15, acc[i][j][jj]);
        }
      }
    }
  }
}

extern "C" void kernel_launch(void* const* d_in, const int* in_sizes, int n_in,
                              void* d_out, int out_size, void* d_ws, size_t ws_size,
                              hipStream_t stream) {
  const float* batch = (const float*)d_in[0];
  const int*   cls   = (const int*)d_in[1];
  const float* W     = (const float*)d_in[2];
  float* out = (float*)d_out;
  int*   ws  = (int*)d_ws;

  prep_kernel<<<1, 256, 0, stream>>>(cls, ws);
  hipMemsetAsync(d_out, 0, (size_t)out_size * sizeof(float), stream);
  gemm_kernel<<<dim3(MAXTILES, NOUT / BN, NSPLIT), 256, 0, stream>>>(batch, W, ws, out);
}

// Round 4
// 311.460 us; speedup vs baseline: 1.1874x; 1.0099x over previous
//
#include <hip/hip_runtime.h>
#include <hip/hip_bf16.h>

typedef __attribute__((ext_vector_type(4))) float f32x4;
typedef __attribute__((ext_vector_type(8))) short s16x8;

#define NCLS 16
#define NCAT 4096
#define NOUT 512
#define NBS  4096

#define BM 128
#define BN 64
#define BK 32
#define NSPLIT 4
#define KSPLIT (NCAT / NSPLIT)   // 1024
#define NIT    (KSPLIT / BK)     // 32
#define MAXTILES 48
#define BUFSZ  24576             // A 16KB + B 8KB per K-tile buffer

// d_ws int layout
#define WS_NT    0
#define WS_CBASE 1     // [17]
#define WS_TCLS  32    // [MAXTILES]
#define WS_TM0   96    // [MAXTILES]
#define WS_SIDX  160   // [4096]

// ---------------- prep: histogram + parallel scan + tile map + scatter ----------------
__global__ __launch_bounds__(256) void prep_kernel(const int* __restrict__ cls,
                                                   int* __restrict__ ws) {
  __shared__ int lcnt[NCLS * 256];
  __shared__ int cb[NCLS];
  const int t = threadIdx.x;

  int cl[16];
  #pragma unroll
  for (int j = 0; j < 16; ++j) cl[j] = cls[j * 256 + t];

  int cnt[NCLS];
  #pragma unroll
  for (int c = 0; c < NCLS; ++c) cnt[c] = 0;
  #pragma unroll
  for (int j = 0; j < 16; ++j) {
    #pragma unroll
    for (int c = 0; c < NCLS; ++c) cnt[c] += (cl[j] == c) ? 1 : 0;
  }
  #pragma unroll
  for (int c = 0; c < NCLS; ++c) lcnt[c * 256 + t] = cnt[c];
  __syncthreads();

  // Hillis-Steele inclusive scan over t for all 16 classes at once
  for (int d = 1; d < 256; d <<= 1) {
    int add[NCLS];
    #pragma unroll
    for (int c = 0; c < NCLS; ++c) add[c] = (t >= d) ? lcnt[c * 256 + t - d] : 0;
    __syncthreads();
    #pragma unroll
    for (int c = 0; c < NCLS; ++c) if (t >= d) lcnt[c * 256 + t] += add[c];
    __syncthreads();
  }

  if (t == 0) {
    int acc = 0, ntt = 0;
    for (int c = 0; c < NCLS; ++c) {
      cb[c] = acc;
      ws[WS_CBASE + c] = acc;
      int tot = lcnt[c * 256 + 255];
      for (int m0 = 0; m0 < tot; m0 += BM) {
        ws[WS_TCLS + ntt] = c;
        ws[WS_TM0 + ntt] = m0;
        ++ntt;
      }
      acc += tot;
    }
    ws[WS_CBASE + NCLS] = acc;
    ws[WS_NT] = ntt;
  }
  __syncthreads();

  #pragma unroll
  for (int j = 0; j < 16; ++j) {
    int c = cl[j];
    int within = 0;
    #pragma unroll
    for (int j2 = 0; j2 < 16; ++j2) within += (j2 < j && cl[j2] == c) ? 1 : 0;
    ws[WS_SIDX + cb[c] + (lcnt[c * 256 + t] - cnt[c]) + within] = j * 256 + t;
  }
}

// ---------------- gemm helpers ----------------
typedef const __attribute__((address_space(1))) void* gas_ptr;
typedef __attribute__((address_space(3))) void* las_ptr;

__device__ __forceinline__ void gl_lds16(const void* g, void* l) {
  __builtin_amdgcn_global_load_lds((gas_ptr)g, (las_ptr)l, 16, 0, 0);
}

// Split x into hi = bf16_rn(x), lo = bf16_rn(x - hi); packed pairs.
__device__ __forceinline__ void pk2(float x0, float x1, unsigned& hb, unsigned& lb) {
  __hip_bfloat162 h2 = __float22bfloat162_rn(make_float2(x0, x1));
  float2 hf = __bfloat1622float2(h2);
  __hip_bfloat162 l2 = __float22bfloat162_rn(make_float2(x0 - hf.x, x1 - hf.y));
  __builtin_memcpy(&hb, &h2, 4);
  __builtin_memcpy(&lb, &l2, 4);
}

__device__ __forceinline__ void cvt8(f32x4 p, f32x4 q, s16x8& hi, s16x8& lo) {
  union { s16x8 v; unsigned u[4]; } H, L;
  pk2(p[0], p[1], H.u[0], L.u[0]);
  pk2(p[2], p[3], H.u[1], L.u[1]);
  pk2(q[0], q[1], H.u[2], L.u[2]);
  pk2(q[2], q[3], H.u[3], L.u[3]);
  hi = H.v; lo = L.v;
}

// ---------------- grouped GEMM: 2-phase loop, 3 blocks/CU, async DMA ----------------
__global__ __launch_bounds__(256, 3) void gemm_kernel(const float* __restrict__ batch,
                                                      const float* __restrict__ W,
                                                      const int* __restrict__ ws,
                                                      float* __restrict__ out) {
  const int tile = blockIdx.x;
  if (tile >= ws[WS_NT]) return;
  const int c    = ws[WS_TCLS + tile];
  const int m0   = ws[WS_TM0 + tile];
  const int base = ws[WS_CBASE + c];
  const int Mc   = ws[WS_CBASE + c + 1] - base;
  const int n0   = blockIdx.y * BN;
  const int k0   = blockIdx.z * KSPLIT;
  const int* sidx = ws + WS_SIDX + base;

  // LDS: 2 buffers x [ A 128x32 fp32 (16KB) | B 64x32 fp32 (8KB) ]
  __shared__ char lds[2 * BUFSZ];

  const int t    = threadIdx.x;
  const int lane = t & 63;
  const int wv   = t >> 6;
  const int l15  = lane & 15;

  // --- DMA source addresses, pre-swizzled (linear LDS dest == swizzled layout) ---
  // gl_lds16: 1024B = 8 rows x 128B. lane l: row +(l>>3), chunk ((l&7)^(l>>3)).
  const int rsub = lane >> 3;
  const int cswz = (((lane & 7) ^ rsub) << 4);
  const char* aga[4];
  #pragma unroll
  for (int j = 0; j < 4; ++j) {
    const int rr = 32 * wv + 8 * j + rsub;
    const int ar = sidx[min(m0 + rr, Mc - 1)];
    aga[j] = (const char*)batch + ((size_t)ar * NCAT + k0) * 4 + cswz;
  }
  const char* bga[2];
  #pragma unroll
  for (int j = 0; j < 2; ++j) {
    const int br = c * NOUT + n0 + 16 * wv + 8 * j + rsub;
    bga[j] = (const char*)W + ((size_t)br * NCAT + k0) * 4 + cswz;
  }

  const int wm  = (wv >> 1) * 64;   // wave output block: 64 rows x 32 cols
  const int wn  = (wv & 1) * 32;
  const int kb0 = (lane >> 4) * 32; // lane's 8-float k-group byte base
  const int swz = (l15 & 7) << 4;   // read-side XOR (m&7 == n&7 == l15&7)

  f32x4 acc[4][2];
  #pragma unroll
  for (int i = 0; i < 4; ++i)
    #pragma unroll
    for (int j = 0; j < 2; ++j) acc[i][j] = (f32x4){0.f, 0.f, 0.f, 0.f};

  #define STAGE(bufofs, kbyte)                                                  \
    do {                                                                        \
      _Pragma("unroll")                                                         \
      for (int j = 0; j < 4; ++j)                                               \
        gl_lds16(aga[j] + (kbyte), lds + (bufofs) + (32 * wv + 8 * j) * 128);   \
      _Pragma("unroll")                                                         \
      for (int j = 0; j < 2; ++j)                                               \
        gl_lds16(bga[j] + (kbyte), lds + (bufofs) + 16384 + (16 * wv + 8 * j) * 128); \
    } while (0)

  // prologue: stage tile 0, drain, barrier
  STAGE(0, 0);
  asm volatile("s_waitcnt vmcnt(0)" ::: "memory");
  __builtin_amdgcn_s_barrier();
  asm volatile("" ::: "memory");

  int cur = 0;
  for (int it = 0; it < NIT; ++it) {
    // phase 1: issue next tile's DMAs (fly across the compute phase)
    if (it + 1 < NIT) STAGE((cur ^ 1) * BUFSZ, (it + 1) * 128);

    // phase 2: read + convert + MFMA on current buffer
    const char* const bufp = lds + cur * BUFSZ;
    s16x8 Ah[4], Al[4], Bh[2], Bl[2];
    #pragma unroll
    for (int i = 0; i < 4; ++i) {
      const char* rowp = bufp + (wm + i * 16 + l15) * 128;
      f32x4 p = *(const f32x4*)(rowp + (kb0 ^ swz));
      f32x4 q = *(const f32x4*)(rowp + ((kb0 + 16) ^ swz));
      cvt8(p, q, Ah[i], Al[i]);
    }
    #pragma unroll
    for (int j = 0; j < 2; ++j) {
      const char* rowq = bufp + 16384 + (wn + j * 16 + l15) * 128;
      f32x4 r = *(const f32x4*)(rowq + (kb0 ^ swz));
      f32x4 s = *(const f32x4*)(rowq + ((kb0 + 16) ^ swz));
      cvt8(r, s, Bh[j], Bl[j]);
    }
    #pragma unroll
    for (int i = 0; i < 4; ++i)
      #pragma unroll
      for (int j = 0; j < 2; ++j) {
        acc[i][j] = __builtin_amdgcn_mfma_f32_16x16x32_bf16(Ah[i], Bh[j], acc[i][j], 0, 0, 0);
        acc[i][j] = __builtin_amdgcn_mfma_f32_16x16x32_bf16(Ah[i], Bl[j], acc[i][j], 0, 0, 0);
        acc[i][j] = __builtin_amdgcn_mfma_f32_16x16x32_bf16(Al[i], Bh[j], acc[i][j], 0, 0, 0);
      }

    // phase 3: pin schedule, drain this iter's DMAs, barrier
    __builtin_amdgcn_sched_barrier(0);
    asm volatile("s_waitcnt vmcnt(0)" ::: "memory");
    __builtin_amdgcn_s_barrier();
    asm volatile("" ::: "memory");
    cur ^= 1;
  }
  #undef STAGE

  // ---- epilogue: C/D layout col=lane&15, row=(lane>>4)*4+reg ----
  const int r4 = (lane >> 4) * 4;
  #pragma unroll
  for (int i = 0; i < 4; ++i) {
    #pragma unroll
    for (int jj = 0; jj < 4; ++jj) {
      const int mloc = wm + i * 16 + r4 + jj;
      const int gm = m0 + mloc;
      if (gm < Mc) {
        const int sample = sidx[gm];
        float* orow = out + (size_t)sample * NOUT + n0 + wn;
        #pragma unroll
        for (int j = 0; j < 2; ++j) {
          atomicAdd(orow + j * 16 + l15, acc[i][j][jj]);
        }
      }
    }
  }
}

extern "C" void kernel_launch(void* const* d_in, const int* in_sizes, int n_in,
                              void* d_out, int out_size, void* d_ws, size_t ws_size,
                              hipStream_t stream) {
  const float* batch = (const float*)d_in[0];
  const int*   cls   = (const int*)d_in[1];
  const float* W     = (const float*)d_in[2];
  float* out = (float*)d_out;
  int*   ws  = (int*)d_ws;

  prep_kernel<<<1, 256, 0, stream>>>(cls, ws);
  hipMemsetAsync(d_out, 0, (size_t)out_size * sizeof(float), stream);
  gemm_kernel<<<dim3(MAXTILES, NOUT / BN, NSPLIT), 256, 0, stream>>>(batch, W, ws, out);
}